// Round 1
// baseline (524.984 us; speedup 1.0000x reference)
//
#include <hip/hip_runtime.h>
#include <math.h>

#define N_   64
#define C_   512
#define HW_  1024
#define K_   64
#define ALPHA_ 50.0f
#define EPS_  1e-12f

// d_out float offsets
#define OUT_VLAD 0
#define OUT_SA   2097152     // N*K*C = 64*64*512
#define OUT_FEAT 6291456     // + N*K*HW

// ws float offsets
#define WS_WNT  0            // [K][C] normalized W^T
#define WS_WT   32768        // [K][C] original W^T
#define WS_A    65536        // [N][K][HW] soft assign
#define WS_SUMA 4259840      // [N*K]
#define WS_PART 4263936      // 4 x [N*K*C] partial vlad
#define PART_STRIDE 2097152

// ---------------- K1: weight norms -> wnT (normalized), wT (original), [K][C]
__global__ __launch_bounds__(256) void k1_weights(const float* __restrict__ W,
                                                  float* __restrict__ ws) {
    float* wnT = ws + WS_WNT;
    float* wT  = ws + WS_WT;
    int k = blockIdx.x;
    int t = threadIdx.x;
    __shared__ float red[256];
    float s = 0.f;
    for (int c = t; c < C_; c += 256) { float w = W[c * K_ + k]; s += w * w; }
    red[t] = s;
    __syncthreads();
    for (int st = 128; st > 0; st >>= 1) {
        if (t < st) red[t] += red[t + st];
        __syncthreads();
    }
    float inv = 1.f / fmaxf(sqrtf(red[0]), EPS_);
    for (int c = t; c < C_; c += 256) {
        float w = W[c * K_ + k];
        wnT[k * C_ + c] = w * inv;
        wT[k * C_ + c]  = w;
    }
}

// ---------------- K2: L2-normalize x over C, write feature [N][HW][C]
__global__ __launch_bounds__(256) void k2_normfeat(const float* __restrict__ x,
                                                   float* __restrict__ out) {
    float* feat = out + OUT_FEAT;
    int b   = blockIdx.x;
    int n   = b >> 6;            // 64 tiles of 16 pixels per n
    int hw0 = (b & 63) << 4;
    int t   = threadIdx.x;
    __shared__ float Xs[C_ * 17 + 256 + 16];  // tile + red + nrm
    float* red = Xs + C_ * 17;
    float* nrm = red + 256;
    const float* xn = x + (long)n * C_ * HW_;
    for (int j = 0; j < 32; ++j) {
        int idx = j * 256 + t;
        int c = idx >> 4, p = idx & 15;
        Xs[c * 17 + p] = xn[c * HW_ + hw0 + p];
    }
    __syncthreads();
    {
        int p = t & 15, cg = t >> 4;
        float s = 0.f;
        for (int j = 0; j < 32; ++j) {
            float v = Xs[(cg + 16 * j) * 17 + p];
            s += v * v;
        }
        red[t] = s;
    }
    __syncthreads();
    if (t < 16) {
        float s = 0.f;
        for (int g = 0; g < 16; ++g) s += red[g * 16 + t];
        nrm[t] = 1.f / fmaxf(sqrtf(s), EPS_);
    }
    __syncthreads();
    float* frow = feat + ((long)n * HW_ + hw0) * C_;
    for (int p = 0; p < 16; ++p) {
        float iv = nrm[p];
        float v0 = Xs[t * 17 + p] * iv;
        float v1 = Xs[(t + 256) * 17 + p] * iv;
        frow[(long)p * C_ + t]       = v0;
        frow[(long)p * C_ + t + 256] = v1;
    }
}

// ---------------- K3: GEMM1 (logits = feature . Wn) + softmax -> sa_logits, A
#define K3P 68   // LDS pitch, multiple of 4 for b128 alignment
__global__ __launch_bounds__(256) void k3_sa(const float* __restrict__ feat,
                                             const float* __restrict__ wnT,
                                             const float* __restrict__ bias,
                                             float* __restrict__ sa,
                                             float* __restrict__ A) {
    __shared__ float sm[13056];          // 52.2 KB
    float* Fs = sm;                       // [128][68]
    float* Ws = sm + 128 * K3P;           // [64][68] at 8704
    // phase-2 overlay (after syncthreads):
    float* Ls = sm;                       // [64][132] = 8448
    float* Bz = sm + 8448;                // 64
    float* Zm = sm + 8512;                // 128
    float* Iv = sm + 8640;                // 128

    int b   = blockIdx.x;
    int n   = b >> 3;
    int hw0 = (b & 7) << 7;               // 128-pixel tile
    int t   = threadIdx.x;
    int l   = t & 63, wv = t >> 6;
    int kcb = wv * 16 + (l >> 4) * 4;     // 4 clusters per thread
    int pl  = l & 15;                     // pixel lane base (strided by 16)

    float acc[8][4];
#pragma unroll
    for (int i = 0; i < 8; ++i)
#pragma unroll
        for (int m = 0; m < 4; ++m) acc[i][m] = 0.f;

    const float* fb = feat + ((long)n * HW_ + hw0) * C_;
    for (int ch = 0; ch < 8; ++ch) {
        int c0 = ch * 64;
        __syncthreads();
#pragma unroll
        for (int j = 0; j < 8; ++j) {     // Fs: 128 x 64
            int f4 = j * 256 + t;
            int p = f4 >> 4, c4 = (f4 & 15) << 2;
            float4 v = *(const float4*)(fb + (long)p * C_ + c0 + c4);
            *(float4*)(Fs + p * K3P + c4) = v;
        }
#pragma unroll
        for (int j = 0; j < 4; ++j) {     // Ws: 64 x 64
            int f4 = j * 256 + t;
            int kc = f4 >> 4, c4 = (f4 & 15) << 2;
            float4 v = *(const float4*)(wnT + kc * C_ + c0 + c4);
            *(float4*)(Ws + kc * K3P + c4) = v;
        }
        __syncthreads();
#pragma unroll
        for (int cc = 0; cc < 16; ++cc) {
            int c4 = cc * 4;
            float4 w[4];
#pragma unroll
            for (int m = 0; m < 4; ++m)
                w[m] = *(const float4*)(Ws + (kcb + m) * K3P + c4);
#pragma unroll
            for (int i = 0; i < 8; ++i) {
                float4 f = *(const float4*)(Fs + (pl + 16 * i) * K3P + c4);
#pragma unroll
                for (int m = 0; m < 4; ++m)
                    acc[i][m] += f.x * w[m].x + f.y * w[m].y + f.z * w[m].z + f.w * w[m].w;
            }
        }
    }
    __syncthreads();
    // dump logits to LDS [kc][128p]
#pragma unroll
    for (int i = 0; i < 8; ++i)
#pragma unroll
        for (int m = 0; m < 4; ++m)
            Ls[(kcb + m) * 132 + pl + 16 * i] = acc[i][m];
    if (t < 64) Bz[t] = bias[t];
    __syncthreads();
    if (t < 128) {
        int p = t;
        float mx = -1e30f;
        for (int kc = 0; kc < 64; ++kc) {
            float z = (Ls[kc * 132 + p] + Bz[kc]) * ALPHA_;
            mx = fmaxf(mx, z);
        }
        float s = 0.f;
        for (int kc = 0; kc < 64; ++kc) {
            float z = (Ls[kc * 132 + p] + Bz[kc]) * ALPHA_;
            s += __expf(z - mx);
        }
        Zm[p] = mx;
        Iv[p] = 1.f / s;
    }
    __syncthreads();
    float* sab = sa + (long)n * K_ * HW_ + hw0;
    float* Ab  = A  + (long)n * K_ * HW_ + hw0;
#pragma unroll
    for (int j = 0; j < 32; ++j) {
        int idx = j * 256 + t;
        int kc = idx >> 7, p = idx & 127;
        float v = Ls[kc * 132 + p];
        sab[(long)kc * HW_ + p] = v;                       // raw logits output
        float z = (v + Bz[kc]) * ALPHA_;
        Ab[(long)kc * HW_ + p] = __expf(z - Zm[p]) * Iv[p];
    }
}

// ---------------- K3b: sumA[n,k] = sum_h A[n,k,h]
__global__ __launch_bounds__(256) void k3b_suma(const float* __restrict__ A,
                                                float* __restrict__ sumA) {
    int b = blockIdx.x, t = threadIdx.x;
    int wv = t >> 6, l = t & 63;
    int row = b * 4 + wv;
    const float* ar = A + (long)row * HW_;
    float s = 0.f;
#pragma unroll
    for (int i = 0; i < 16; ++i) s += ar[l + 64 * i];
#pragma unroll
    for (int off = 32; off > 0; off >>= 1) s += __shfl_down(s, off, 64);
    if (l == 0) sumA[row] = s;
}

// ---------------- K4: raw vlad partials = A . feature  (per h-quarter, c-tile)
#define K4AP 68
#define K4FP 260
__global__ __launch_bounds__(256) void k4_vlad(const float* __restrict__ A,
                                               const float* __restrict__ feat,
                                               float* __restrict__ part) {
    __shared__ float sm[32 * K4AP + 32 * K4FP];  // 42 KB
    float* As = sm;                 // [32h][68k] (transposed)
    float* Fs = sm + 32 * K4AP;     // [32h][260c]
    int b  = blockIdx.x;
    int n  = b >> 3;
    int r  = b & 7;
    int ct = r & 1, hq = r >> 1;
    int c_off = ct * 256, h_off = hq * 256;
    int t = threadIdx.x;
    int l = t & 63, wv = t >> 6;
    int kcb = (wv >> 1) * 32 + (l >> 4) * 8;
    int cb  = (wv & 1) * 128 + (l & 15) * 8;

    float acc[8][8];
#pragma unroll
    for (int i = 0; i < 8; ++i)
#pragma unroll
        for (int j = 0; j < 8; ++j) acc[i][j] = 0.f;

    const float* Ab = A + (long)n * K_ * HW_ + h_off;
    const float* fb = feat + ((long)n * HW_ + h_off) * C_ + c_off;

    for (int ch = 0; ch < 8; ++ch) {
        int h0 = ch * 32;
        __syncthreads();
#pragma unroll
        for (int j = 0; j < 2; ++j) {    // stage A transposed: 64k x 32h
            int a4 = j * 256 + t;
            int kc = a4 >> 3, h4 = (a4 & 7) << 2;
            float4 v = *(const float4*)(Ab + (long)kc * HW_ + h0 + h4);
            As[(h4 + 0) * K4AP + kc] = v.x;
            As[(h4 + 1) * K4AP + kc] = v.y;
            As[(h4 + 2) * K4AP + kc] = v.z;
            As[(h4 + 3) * K4AP + kc] = v.w;
        }
#pragma unroll
        for (int j = 0; j < 8; ++j) {    // stage feature: 32h x 256c
            int f4 = j * 256 + t;
            int h = f4 >> 6, c4 = (f4 & 63) << 2;
            float4 v = *(const float4*)(fb + (long)(h0 + h) * C_ + c4);
            *(float4*)(Fs + h * K4FP + c4) = v;
        }
        __syncthreads();
#pragma unroll 4
        for (int hh = 0; hh < 32; ++hh) {
            float4 a0 = *(const float4*)(As + hh * K4AP + kcb);
            float4 a1 = *(const float4*)(As + hh * K4AP + kcb + 4);
            float4 f0 = *(const float4*)(Fs + hh * K4FP + cb);
            float4 f1 = *(const float4*)(Fs + hh * K4FP + cb + 4);
            float av[8] = {a0.x, a0.y, a0.z, a0.w, a1.x, a1.y, a1.z, a1.w};
            float fv[8] = {f0.x, f0.y, f0.z, f0.w, f1.x, f1.y, f1.z, f1.w};
#pragma unroll
            for (int ki = 0; ki < 8; ++ki)
#pragma unroll
                for (int ci = 0; ci < 8; ++ci)
                    acc[ki][ci] += av[ki] * fv[ci];
        }
    }
    float* pb = part + (long)hq * PART_STRIDE + (long)n * K_ * C_ + c_off;
#pragma unroll
    for (int ki = 0; ki < 8; ++ki) {
        float4 v0 = make_float4(acc[ki][0], acc[ki][1], acc[ki][2], acc[ki][3]);
        float4 v1 = make_float4(acc[ki][4], acc[ki][5], acc[ki][6], acc[ki][7]);
        *(float4*)(pb + (long)(kcb + ki) * C_ + cb)     = v0;
        *(float4*)(pb + (long)(kcb + ki) * C_ + cb + 4) = v1;
    }
}

// ---------------- K5: combine partials, subtract sumA*W, intra-normalize
__global__ __launch_bounds__(256) void k5_norm(const float* __restrict__ part,
                                               const float* __restrict__ sumA,
                                               const float* __restrict__ wT,
                                               float* __restrict__ vlad) {
    __shared__ float red[256];
    int row = blockIdx.x;        // n*64 + kc
    int kc  = row & 63;
    int t   = threadIdx.x;
    float sA = sumA[row];
    long base = (long)row * C_;
    float v0, v1;
    {
        int c = t;
        float s = part[base + c] + part[PART_STRIDE + base + c]
                + part[2 * PART_STRIDE + base + c] + part[3 * PART_STRIDE + base + c];
        v0 = s - sA * wT[kc * C_ + c];
    }
    {
        int c = t + 256;
        float s = part[base + c] + part[PART_STRIDE + base + c]
                + part[2 * PART_STRIDE + base + c] + part[3 * PART_STRIDE + base + c];
        v1 = s - sA * wT[kc * C_ + c];
    }
    red[t] = v0 * v0 + v1 * v1;
    __syncthreads();
    for (int st = 128; st > 0; st >>= 1) {
        if (t < st) red[t] += red[t + st];
        __syncthreads();
    }
    float inv = 1.f / fmaxf(sqrtf(red[0]), EPS_);
    vlad[base + t]       = v0 * inv;
    vlad[base + t + 256] = v1 * inv;
}

extern "C" void kernel_launch(void* const* d_in, const int* in_sizes, int n_in,
                              void* d_out, int out_size, void* d_ws, size_t ws_size,
                              hipStream_t stream) {
    const float* x    = (const float*)d_in[0];
    const float* W    = (const float*)d_in[1];
    const float* bias = (const float*)d_in[2];
    float* out = (float*)d_out;
    float* ws  = (float*)d_ws;

    float* wnT  = ws + WS_WNT;
    float* wT   = ws + WS_WT;
    float* A    = ws + WS_A;
    float* sumA = ws + WS_SUMA;
    float* part = ws + WS_PART;
    float* vlad = out + OUT_VLAD;
    float* sa   = out + OUT_SA;
    float* feat = out + OUT_FEAT;

    hipLaunchKernelGGL(k1_weights, dim3(64),   dim3(256), 0, stream, W, ws);
    hipLaunchKernelGGL(k2_normfeat, dim3(4096), dim3(256), 0, stream, x, out);
    hipLaunchKernelGGL(k3_sa,      dim3(512),  dim3(256), 0, stream, feat, wnT, bias, sa, A);
    hipLaunchKernelGGL(k3b_suma,   dim3(1024), dim3(256), 0, stream, A, sumA);
    hipLaunchKernelGGL(k4_vlad,    dim3(512),  dim3(256), 0, stream, A, feat, part);
    hipLaunchKernelGGL(k5_norm,    dim3(4096), dim3(256), 0, stream, part, sumA, wT, vlad);
}

// Round 2
// 358.540 us; speedup vs baseline: 1.4642x; 1.4642x over previous
//
#include <hip/hip_runtime.h>
#include <math.h>

#define N_   64
#define C_   512
#define HW_  1024
#define K_   64
#define ALPHA_ 50.0f
#define EPS_  1e-12f

// d_out float offsets
#define OUT_VLAD 0
#define OUT_SA   2097152     // N*K*C
#define OUT_FEAT 6291456     // + N*K*HW

// ws byte offsets (total ~25.6 MB, well under round-1's proven 50.6 MB)
#define WSB_WT    0           // fp32 [K][C]           131072 B
#define WSB_WNTB  131072      // bf16 [K][C]            65536 B
#define WSB_INVN  196608      // fp32 [N][HW]          262144 B
#define WSB_A     458752      // bf16 [N][K][HW]      8388608 B
#define WSB_SUMA  8847360     // fp32 [N*K]             16384 B
#define WSB_PART  8863744     // fp32 2x[N][K][C]    16777216 B
#define PART_ELEMS 2097152    // floats per partial copy

typedef __attribute__((ext_vector_type(8))) __bf16 bf16x8;
typedef __attribute__((ext_vector_type(4))) float f32x4;
typedef __attribute__((ext_vector_type(8))) unsigned short ushort8v;

__device__ inline unsigned short f2bf(float f) {
    unsigned int u = __builtin_bit_cast(unsigned int, f);
    u = (u + 0x7FFFu + ((u >> 16) & 1u)) >> 16;
    return (unsigned short)u;
}
__device__ inline float bf2f(unsigned short h) {
    unsigned int u = ((unsigned int)h) << 16;
    return __builtin_bit_cast(float, u);
}
__device__ inline f32x4 mfma16(const unsigned short* pa, const unsigned short* pb, f32x4 c) {
    bf16x8 a = *(const bf16x8*)pa;
    bf16x8 b = *(const bf16x8*)pb;
    return __builtin_amdgcn_mfma_f32_16x16x32_bf16(a, b, c, 0, 0, 0);
}

// ---------------- K1: weight column norms -> wT fp32, wnTb bf16, both [K][C]
__global__ __launch_bounds__(256) void k1_weights(const float* __restrict__ W,
                                                  float* __restrict__ wT,
                                                  unsigned short* __restrict__ wnTb) {
    int k = blockIdx.x;
    int t = threadIdx.x;
    __shared__ float red[256];
    float s = 0.f;
    for (int c = t; c < C_; c += 256) { float w = W[c * K_ + k]; s += w * w; }
    red[t] = s;
    __syncthreads();
    for (int st = 128; st > 0; st >>= 1) {
        if (t < st) red[t] += red[t + st];
        __syncthreads();
    }
    float inv = 1.f / fmaxf(sqrtf(red[0]), EPS_);
    for (int c = t; c < C_; c += 256) {
        float w = W[c * K_ + k];
        wT[k * C_ + c]   = w;
        wnTb[k * C_ + c] = f2bf(w * inv);
    }
}

// ---------------- K2: L2-normalize x over C, write feature [N][HW][C] + invn
__global__ __launch_bounds__(256) void k2_normfeat(const float* __restrict__ x,
                                                   float* __restrict__ out,
                                                   float* __restrict__ invn) {
    float* feat = out + OUT_FEAT;
    int b   = blockIdx.x;
    int n   = b >> 6;
    int hw0 = (b & 63) << 4;
    int t   = threadIdx.x;
    __shared__ float Xs[C_ * 17 + 256 + 16];
    float* red = Xs + C_ * 17;
    float* nrm = red + 256;
    const float* xn = x + (long)n * C_ * HW_;
    for (int j = 0; j < 32; ++j) {
        int idx = j * 256 + t;
        int c = idx >> 4, p = idx & 15;
        Xs[c * 17 + p] = xn[c * HW_ + hw0 + p];
    }
    __syncthreads();
    {
        int p = t & 15, cg = t >> 4;
        float s = 0.f;
        for (int j = 0; j < 32; ++j) {
            float v = Xs[(cg + 16 * j) * 17 + p];
            s += v * v;
        }
        red[t] = s;
    }
    __syncthreads();
    if (t < 16) {
        float s = 0.f;
        for (int g = 0; g < 16; ++g) s += red[g * 16 + t];
        float iv = 1.f / fmaxf(sqrtf(s), EPS_);
        nrm[t] = iv;
        invn[(long)n * HW_ + hw0 + t] = iv;
    }
    __syncthreads();
    float* frow = feat + ((long)n * HW_ + hw0) * C_;
    for (int p = 0; p < 16; ++p) {
        float iv = nrm[p];
        frow[(long)p * C_ + t]       = Xs[t * 17 + p] * iv;
        frow[(long)p * C_ + t + 256] = Xs[(t + 256) * 17 + p] * iv;
    }
}

// ---------------- K3: MFMA GEMM1 (logits = feat . WnT) + softmax -> sa, A(bf16)
#define K3PITCH 136   // bf16 elems; 272 B row, 16B aligned, 2-way bank max
__global__ __launch_bounds__(256, 4) void k3_sa(const float* __restrict__ feat,
                                                const unsigned short* __restrict__ wnTb,
                                                const float* __restrict__ bias,
                                                float* __restrict__ sa,
                                                unsigned short* __restrict__ Ab) {
    __shared__ alignas(16) unsigned short sm[128 * K3PITCH + 64 * K3PITCH]; // 52224 B
    unsigned short* Fsh = sm;
    unsigned short* Wsh = sm + 128 * K3PITCH;
    // phase-2 overlay
    float* Ls = (float*)sm;        // [64][132]
    float* Bz = Ls + 8448;
    float* Zm = Ls + 8512;
    float* Iv = Ls + 8640;

    int b   = blockIdx.x;
    int n   = b >> 3;
    int hw0 = (b & 7) << 7;
    int t   = threadIdx.x;
    int l   = t & 63, w = t >> 6;
    int mr  = l & 15, q = l >> 4;

    f32x4 acc[2][4];
#pragma unroll
    for (int i = 0; i < 2; ++i)
#pragma unroll
        for (int j = 0; j < 4; ++j) acc[i][j] = (f32x4){0.f, 0.f, 0.f, 0.f};

    const float* fb = feat + ((long)n * HW_ + hw0) * C_;
    for (int ch = 0; ch < 4; ++ch) {
        int c0 = ch * 128;
        __syncthreads();
#pragma unroll
        for (int j = 0; j < 8; ++j) {          // Fsh: 128p x 128c (cvt fp32->bf16)
            int idx = j * 256 + t;
            int row = idx >> 4, sg = idx & 15;
            const float* src = fb + (long)row * C_ + c0 + sg * 8;
            float4 v0 = *(const float4*)src;
            float4 v1 = *(const float4*)(src + 4);
            ushort8v pk;
            pk[0] = f2bf(v0.x); pk[1] = f2bf(v0.y); pk[2] = f2bf(v0.z); pk[3] = f2bf(v0.w);
            pk[4] = f2bf(v1.x); pk[5] = f2bf(v1.y); pk[6] = f2bf(v1.z); pk[7] = f2bf(v1.w);
            *(ushort8v*)(Fsh + row * K3PITCH + sg * 8) = pk;
        }
#pragma unroll
        for (int j = 0; j < 4; ++j) {          // Wsh: 64k x 128c (bf16 copy)
            int idx = j * 256 + t;
            int row = idx >> 4, sg = idx & 15;
            *(uint4*)(Wsh + row * K3PITCH + sg * 8) =
                *(const uint4*)(wnTb + row * C_ + c0 + sg * 8);
        }
        __syncthreads();
#pragma unroll
        for (int ks = 0; ks < 4; ++ks) {
            int ko = ks * 32 + q * 8;
            const unsigned short* ap0 = Fsh + (w * 32 + mr) * K3PITCH + ko;
            const unsigned short* ap1 = Fsh + (w * 32 + 16 + mr) * K3PITCH + ko;
#pragma unroll
            for (int j = 0; j < 4; ++j) {
                const unsigned short* bp = Wsh + (j * 16 + mr) * K3PITCH + ko;
                acc[0][j] = mfma16(ap0, bp, acc[0][j]);
                acc[1][j] = mfma16(ap1, bp, acc[1][j]);
            }
        }
    }
    __syncthreads();
    // dump logits: D row=(q*4+r)=pixel, col=mr-ish=cluster
#pragma unroll
    for (int i = 0; i < 2; ++i)
#pragma unroll
        for (int j = 0; j < 4; ++j)
#pragma unroll
            for (int r = 0; r < 4; ++r)
                Ls[(j * 16 + mr) * 132 + w * 32 + i * 16 + q * 4 + r] = acc[i][j][r];
    if (t < 64) Bz[t] = bias[t];
    __syncthreads();
    if (t < 128) {
        int p = t;
        float mx = -1e30f;
        for (int kc = 0; kc < 64; ++kc) {
            float z = (Ls[kc * 132 + p] + Bz[kc]) * ALPHA_;
            mx = fmaxf(mx, z);
        }
        float s = 0.f;
        for (int kc = 0; kc < 64; ++kc) {
            float z = (Ls[kc * 132 + p] + Bz[kc]) * ALPHA_;
            s += __expf(z - mx);
        }
        Zm[p] = mx;
        Iv[p] = 1.f / s;
    }
    __syncthreads();
    float* sab = sa + (long)n * K_ * HW_ + hw0;
    unsigned short* Arow = Ab + (long)n * K_ * HW_ + hw0;
#pragma unroll
    for (int j = 0; j < 32; ++j) {
        int idx = j * 256 + t;
        int kc = idx >> 7, p = idx & 127;
        float v = Ls[kc * 132 + p];
        sab[(long)kc * HW_ + p] = v;
        float z = (v + Bz[kc]) * ALPHA_;
        Arow[(long)kc * HW_ + p] = f2bf(__expf(z - Zm[p]) * Iv[p]);
    }
}

// ---------------- K3b: sumA[n,k] = sum_h A[n,k,h]  (A is bf16)
__global__ __launch_bounds__(256) void k3b_suma(const unsigned short* __restrict__ Ab,
                                                float* __restrict__ sumA) {
    int b = blockIdx.x, t = threadIdx.x;
    int wv = t >> 6, l = t & 63;
    int row = b * 4 + wv;
    const unsigned int* ar = (const unsigned int*)(Ab + (long)row * HW_);
    float s = 0.f;
#pragma unroll
    for (int i = 0; i < 8; ++i) {
        unsigned int u = ar[i * 64 + l];
        s += bf2f((unsigned short)(u & 0xFFFF)) + bf2f((unsigned short)(u >> 16));
    }
#pragma unroll
    for (int off = 32; off > 0; off >>= 1) s += __shfl_down(s, off, 64);
    if (l == 0) sumA[row] = s;
}

// ---------------- K4: MFMA GEMM2 vlad_raw = A . feat  (B from x*invn, no transpose)
#define K4PITCH 72    // bf16; 144 B rows, 16B aligned
__global__ __launch_bounds__(256, 4) void k4_vlad(const float* __restrict__ x,
                                                  const float* __restrict__ invn,
                                                  const unsigned short* __restrict__ Ab,
                                                  float* __restrict__ part) {
    __shared__ float invs[512];
    __shared__ alignas(16) unsigned short Ash[64 * K4PITCH];    // 9216 B
    __shared__ alignas(16) unsigned short Fsh[128 * K4PITCH];   // 18432 B
    int b  = blockIdx.x;
    int n  = b >> 3;
    int r  = b & 7;
    int ct = r & 3, hh = r >> 2;
    int c_off = ct * 128, h_base = hh * 512;
    int t = threadIdx.x;
    int l = t & 63, w = t >> 6;
    int mr = l & 15, q = l >> 4;
    int kcb = (w >> 1) * 32, cb = (w & 1) * 64;

    invs[t]       = invn[(long)n * HW_ + h_base + t];
    invs[t + 256] = invn[(long)n * HW_ + h_base + 256 + t];

    f32x4 acc[2][4];
#pragma unroll
    for (int i = 0; i < 2; ++i)
#pragma unroll
        for (int j = 0; j < 4; ++j) acc[i][j] = (f32x4){0.f, 0.f, 0.f, 0.f};

    const unsigned short* Abase = Ab + (long)n * K_ * HW_ + h_base;
    const float* xbase = x + ((long)n * C_ + c_off) * HW_ + h_base;

    for (int ch = 0; ch < 8; ++ch) {
        int h0 = ch * 64;
        __syncthreads();
#pragma unroll
        for (int j = 0; j < 2; ++j) {          // Ash: 64kc x 64h (bf16 copy)
            int idx = j * 256 + t;
            int row = idx >> 3, sg = idx & 7;
            *(uint4*)(Ash + row * K4PITCH + sg * 8) =
                *(const uint4*)(Abase + (long)row * HW_ + h0 + sg * 8);
        }
#pragma unroll
        for (int j = 0; j < 4; ++j) {          // Fsh: 128c x 64h (x*invn -> bf16)
            int idx = j * 256 + t;
            int row = idx >> 3, sg = idx & 7;
            const float* src = xbase + (long)row * HW_ + h0 + sg * 8;
            float4 v0 = *(const float4*)src;
            float4 v1 = *(const float4*)(src + 4);
            const float* iv = invs + h0 + sg * 8;
            ushort8v pk;
            pk[0] = f2bf(v0.x * iv[0]); pk[1] = f2bf(v0.y * iv[1]);
            pk[2] = f2bf(v0.z * iv[2]); pk[3] = f2bf(v0.w * iv[3]);
            pk[4] = f2bf(v1.x * iv[4]); pk[5] = f2bf(v1.y * iv[5]);
            pk[6] = f2bf(v1.z * iv[6]); pk[7] = f2bf(v1.w * iv[7]);
            *(ushort8v*)(Fsh + row * K4PITCH + sg * 8) = pk;
        }
        __syncthreads();
#pragma unroll
        for (int ks = 0; ks < 2; ++ks) {
            int ko = ks * 32 + q * 8;
            const unsigned short* ap0 = Ash + (kcb + mr) * K4PITCH + ko;
            const unsigned short* ap1 = Ash + (kcb + 16 + mr) * K4PITCH + ko;
#pragma unroll
            for (int j = 0; j < 4; ++j) {
                const unsigned short* bp = Fsh + (cb + j * 16 + mr) * K4PITCH + ko;
                acc[0][j] = mfma16(ap0, bp, acc[0][j]);
                acc[1][j] = mfma16(ap1, bp, acc[1][j]);
            }
        }
    }
    float* pb = part + (long)hh * PART_ELEMS + (long)n * K_ * C_ + c_off;
#pragma unroll
    for (int i = 0; i < 2; ++i)
#pragma unroll
        for (int j = 0; j < 4; ++j)
#pragma unroll
            for (int r = 0; r < 4; ++r) {
                int kc = kcb + i * 16 + q * 4 + r;
                int c  = cb + j * 16 + mr;
                pb[(long)kc * C_ + c] = acc[i][j][r];
            }
}

// ---------------- K5: combine 2 partials, subtract sumA*W, intra-normalize
__global__ __launch_bounds__(256) void k5_norm(const float* __restrict__ part,
                                               const float* __restrict__ sumA,
                                               const float* __restrict__ wT,
                                               float* __restrict__ vlad) {
    __shared__ float red[256];
    int row = blockIdx.x;        // n*64 + kc
    int kc  = row & 63;
    int t   = threadIdx.x;
    float sA = sumA[row];
    long base = (long)row * C_;
    float v0, v1;
    {
        int c = t;
        float s = part[base + c] + part[PART_ELEMS + base + c];
        v0 = s - sA * wT[kc * C_ + c];
    }
    {
        int c = t + 256;
        float s = part[base + c] + part[PART_ELEMS + base + c];
        v1 = s - sA * wT[kc * C_ + c];
    }
    red[t] = v0 * v0 + v1 * v1;
    __syncthreads();
    for (int st = 128; st > 0; st >>= 1) {
        if (t < st) red[t] += red[t + st];
        __syncthreads();
    }
    float inv = 1.f / fmaxf(sqrtf(red[0]), EPS_);
    vlad[base + t]       = v0 * inv;
    vlad[base + t + 256] = v1 * inv;
}

extern "C" void kernel_launch(void* const* d_in, const int* in_sizes, int n_in,
                              void* d_out, int out_size, void* d_ws, size_t ws_size,
                              hipStream_t stream) {
    const float* x    = (const float*)d_in[0];
    const float* W    = (const float*)d_in[1];
    const float* bias = (const float*)d_in[2];
    float* out = (float*)d_out;
    char* wsb  = (char*)d_ws;

    float* wT           = (float*)(wsb + WSB_WT);
    unsigned short* wnTb = (unsigned short*)(wsb + WSB_WNTB);
    float* invn         = (float*)(wsb + WSB_INVN);
    unsigned short* Ab  = (unsigned short*)(wsb + WSB_A);
    float* sumA         = (float*)(wsb + WSB_SUMA);
    float* part         = (float*)(wsb + WSB_PART);

    float* vlad = out + OUT_VLAD;
    float* sa   = out + OUT_SA;
    float* feat = out + OUT_FEAT;

    hipLaunchKernelGGL(k1_weights, dim3(64),   dim3(256), 0, stream, W, wT, wnTb);
    hipLaunchKernelGGL(k2_normfeat, dim3(4096), dim3(256), 0, stream, x, out, invn);
    hipLaunchKernelGGL(k3_sa,      dim3(512),  dim3(256), 0, stream, feat, wnTb, bias, sa, Ab);
    hipLaunchKernelGGL(k3b_suma,   dim3(1024), dim3(256), 0, stream, Ab, sumA);
    hipLaunchKernelGGL(k4_vlad,    dim3(512),  dim3(256), 0, stream, x, invn, Ab, part);
    hipLaunchKernelGGL(k5_norm,    dim3(4096), dim3(256), 0, stream, part, sumA, wT, vlad);
}